// Round 4
// baseline (385.669 us; speedup 1.0000x reference)
//
#include <hip/hip_runtime.h>
#include <math.h>

#define N_SLOTS 524288
#define DIM_MEM 128
#define DIM_IN 1024
#define NFACT 138
#define EPSF 1e-8f
#define CPB 4               // chunks per block
#define ROWS_PC 64          // rows per chunk
#define NPAIR 70            // 64 own rows + 3 halo each side
#define PADH 33             // float2 LDS stride -> 2-way bank aliasing only (free)
#define NBLK (N_SLOTS / (CPB * ROWS_PC))   // 2048 blocks
#define PSTRIDE 132         // per-block partial slot: 128 cols + wsum + pad

// ws layout (bytes), first 4096 zeroed each call:
//   0    : float factors[138]
//   1024 : float derived[16]  d0=key_s/key_norm, d1..d7=shift_w, d8=sharpening
//   4096 : float partials[NBLK][PSTRIDE]  (fully written, no zeroing needed)

// ---- Stage 1: factors = x @ W + b  (1024 x 138) ----
__global__ __launch_bounds__(256) void k_factors(const float* __restrict__ x,
                                                 const float* __restrict__ W,
                                                 const float* __restrict__ b,
                                                 float* __restrict__ factors) {
    int j = threadIdx.x;
    int i0 = blockIdx.x * 32;
    if (j < NFACT) {
        float acc = 0.f;
        #pragma unroll 8
        for (int i = i0; i < i0 + 32; ++i)
            acc = fmaf(x[i], W[(size_t)i * NFACT + j], acc);
        if (blockIdx.x == 0) acc += b[j];
        atomicAdd(&factors[j], acc);
    }
}

// ---- Stage 2: derived scalars ----
// gate = softmax over ONE element == 1.0 exactly -> previous_weighting dead.
// Content-softmax denominator cancels in (t/S)^sh / sum(...), never computed.
__global__ void k_derived(const float* __restrict__ f, float* __restrict__ d) {
    int l = threadIdx.x;            // 64 threads
    float v = f[l] * f[l] + f[l + 64] * f[l + 64];
    for (int off = 32; off; off >>= 1) v += __shfl_xor(v, off, 64);
    if (l == 0) {
        float key_norm = fmaxf(sqrtf(v), EPSF);
        d[0] = f[128] / key_norm;
        float m = f[130];
        for (int j = 1; j < 7; ++j) m = fmaxf(m, f[130 + j]);
        float e[7], s = 0.f;
        for (int j = 0; j < 7; ++j) { e[j] = expf(f[130 + j] - m); s += e[j]; }
        for (int j = 0; j < 7; ++j) d[1 + j] = e[j] / s;
        d[8] = fmaxf(f[137], 0.f) + 1.f;
    }
}

// ---- Stage 3: fused single pass, register-double-buffered ----
__global__ __launch_bounds__(256) void k_main(const float* __restrict__ mem,
                                              const float* __restrict__ keyv,
                                              const float* __restrict__ der,
                                              float* __restrict__ partials) {
    __shared__ float2 part2[NPAIR * PADH];   // (dot,n2) partials, [p*PADH + lane]
    __shared__ float e_sh[NPAIR];            // 0..2 left halo, 3..66 own, 67..69 right halo
    __shared__ float w_sh[ROWS_PC];
    __shared__ float colpart[8][DIM_MEM];
    __shared__ float psum[8];

    const int tid  = threadIdx.x;
    const int lane = tid & 31;               // 4 columns each
    const int hw   = tid >> 5;               // 8 half-waves
    const float4* mem4 = (const float4*)mem;
    const float4 k4 = ((const float4*)keyv)[lane];
    const float d0 = der[0];
    const float sharp = der[8];
    float sw[7];
    #pragma unroll
    for (int d = 0; d < 7; ++d) sw[d] = der[1 + d];

    float4 acc = make_float4(0.f, 0.f, 0.f, 0.f);
    float wsum = 0.f;

    float4 bufA[8], bufB[8], haloA, haloB;
    const int base = blockIdx.x * (CPB * ROWS_PC);

    // prologue: load chunk 0
    {
        const int r0 = base, rbase = r0 + hw * 8;
        #pragma unroll
        for (int j = 0; j < 8; ++j)
            bufA[j] = mem4[(size_t)(rbase + j) * 32 + lane];
        if (hw < 6) {
            int hr = (hw < 3) ? (r0 - 3 + hw) : (r0 + ROWS_PC + (hw - 3));
            hr &= (N_SLOTS - 1);
            haloA = mem4[(size_t)hr * 32 + lane];
        }
    }

    #pragma unroll
    for (int c = 0; c < CPB; ++c) {
        float4* cur   = (c & 1) ? bufB : bufA;
        float4* nxt   = (c & 1) ? bufA : bufB;
        float4& curh  = (c & 1) ? haloB : haloA;
        float4& nxth  = (c & 1) ? haloA : haloB;

        // prefetch chunk c+1 (loads in flight across the whole phase train)
        if (c + 1 < CPB) {
            const int r0 = base + (c + 1) * ROWS_PC, rbase = r0 + hw * 8;
            #pragma unroll
            for (int j = 0; j < 8; ++j)
                nxt[j] = mem4[(size_t)(rbase + j) * 32 + lane];
            if (hw < 6) {
                int hr = (hw < 3) ? (r0 - 3 + hw) : (r0 + ROWS_PC + (hw - 3));
                hr &= (N_SLOTS - 1);
                nxth = mem4[(size_t)hr * 32 + lane];
            }
        }

        // Phase A: (dot,n2) partials for own 8 rows + halo, packed float2
        #pragma unroll
        for (int j = 0; j < 8; ++j) {
            float dp = cur[j].x * k4.x + cur[j].y * k4.y + cur[j].z * k4.z + cur[j].w * k4.w;
            float np = cur[j].x * cur[j].x + cur[j].y * cur[j].y + cur[j].z * cur[j].z + cur[j].w * cur[j].w;
            part2[(3 + hw * 8 + j) * PADH + lane] = make_float2(dp, np);
        }
        if (hw < 6) {
            int p = (hw < 3) ? hw : (64 + hw);          // 0..2 and 67..69
            float dp = curh.x * k4.x + curh.y * k4.y + curh.z * k4.z + curh.w * k4.w;
            float np = curh.x * curh.x + curh.y * curh.y + curh.z * curh.z + curh.w * curh.w;
            part2[p * PADH + lane] = make_float2(dp, np);
        }
        __syncthreads();

        // Phase B: 70 threads sum their 32 (dot,n2) pairs and compute e
        if (tid < NPAIR) {
            const float2* q = &part2[tid * PADH];
            float d = 0.f, n = 0.f;
            #pragma unroll
            for (int l = 0; l < 32; ++l) { float2 v = q[l]; d += v.x; n += v.y; }
            e_sh[tid] = __expf(d0 * d / fmaxf(sqrtf(n), EPSF));
        }
        __syncthreads();

        // Phase C: 7-tap stencil + sharpening, one thread per row
        if (tid < ROWS_PC) {
            float t = 0.f;
            #pragma unroll
            for (int d = 0; d < 7; ++d) t = fmaf(sw[d], e_sh[tid + d], t);
            w_sh[tid] = __expf(sharp * __logf(t));      // t > 0 always
        }
        __syncthreads();

        // Phase D: accumulate w * row (w_sh read is half-wave-uniform broadcast)
        #pragma unroll
        for (int j = 0; j < 8; ++j) {
            float w = w_sh[hw * 8 + j];
            acc.x = fmaf(w, cur[j].x, acc.x);
            acc.y = fmaf(w, cur[j].y, acc.y);
            acc.z = fmaf(w, cur[j].z, acc.z);
            acc.w = fmaf(w, cur[j].w, acc.w);
            wsum += w;
        }
        // no barrier here: part2 (written by next A) was fully consumed before bar2,
        // and w_sh (read here) isn't rewritten until after next chunk's bar2.
    }

    // Block epilogue: reduce 8 half-wave partials, write private ws slot (no atomics)
    ((float4*)colpart[hw])[lane] = acc;
    if (lane == 0) psum[hw] = wsum;
    __syncthreads();
    float* slot = partials + (size_t)blockIdx.x * PSTRIDE;
    if (tid < DIM_MEM) {
        float s = 0.f;
        #pragma unroll
        for (int h = 0; h < 8; ++h) s += colpart[h][tid];
        slot[tid] = s;
    }
    if (tid == 0) {
        float s = 0.f;
        #pragma unroll
        for (int h = 0; h < 8; ++h) s += psum[h];
        slot[128] = s;
    }
}

// ---- Stage 4: reduce 2048 block-partials -> out = num / P ----
// grid 128 (one block per column) x 64 threads; partials are L2/L3-resident (1 MB)
__global__ void k_final(const float* __restrict__ partials,
                        float* __restrict__ out) {
    const int c = blockIdx.x, t = threadIdx.x;
    float s = 0.f, p = 0.f;
    for (int b = t; b < NBLK; b += 64) {
        s += partials[(size_t)b * PSTRIDE + c];
        p += partials[(size_t)b * PSTRIDE + 128];
    }
    for (int off = 32; off; off >>= 1) {
        s += __shfl_xor(s, off, 64);
        p += __shfl_xor(p, off, 64);
    }
    if (t == 0) out[c] = s / p;
}

extern "C" void kernel_launch(void* const* d_in, const int* in_sizes, int n_in,
                              void* d_out, int out_size, void* d_ws, size_t ws_size,
                              hipStream_t stream) {
    const float* x   = (const float*)d_in[0];   // input_from_controller (1024)
    // d_in[1] = previous_weighting: unused (gate == 1.0 exactly)
    const float* mem = (const float*)d_in[2];   // memory (N_SLOTS*128)
    const float* W   = (const float*)d_in[3];   // W_wf (1024*138)
    const float* b   = (const float*)d_in[4];   // b_wf (138)
    float* out = (float*)d_out;

    char* ws = (char*)d_ws;
    float* factors  = (float*)ws;
    float* derived  = (float*)(ws + 1024);
    float* partials = (float*)(ws + 4096);

    hipMemsetAsync(ws, 0, 4096, stream);   // factors + derived only

    k_factors<<<DIM_IN / 32, 256, 0, stream>>>(x, W, b, factors);
    k_derived<<<1, 64, 0, stream>>>(factors, derived);
    k_main<<<NBLK, 256, 0, stream>>>(mem, factors, derived, partials);
    k_final<<<DIM_MEM, 64, 0, stream>>>(partials, out);
}